// Round 2
// baseline (470.326 us; speedup 1.0000x reference)
//
#include <hip/hip_runtime.h>

// Problem constants (from reference): T=1024, B=128, C=256, L=64
#define NEG (-1e30f)
constexpr int T = 1024;
constexpr int B = 128;
constexpr int C = 256;
constexpr int L = 64;
constexpr int ENT_GRID = 1024;  // entropy partial blocks
constexpr int K = 16;           // t-steps prefetched per chunk in the DP

// ---------------------------------------------------------------------------
// K1: entropy term. Pure float4 grid-stride stream over T*B*C floats.
// Deterministic per-block partials (no atomics). Memory-bound: ~128 MiB read.
// ---------------------------------------------------------------------------
__global__ __launch_bounds__(256) void k_entropy(const float* __restrict__ lp,
                                                 float* __restrict__ ent_part) {
  const int tid = threadIdx.x;
  const size_t N4 = (size_t)T * B * C / 4;
  const float4* lp4 = (const float4*)lp;
  const size_t stride = (size_t)ENT_GRID * 256;
  float a0 = 0.f, a1 = 0.f, a2 = 0.f, a3 = 0.f;
  for (size_t i = (size_t)blockIdx.x * 256 + tid; i < N4; i += stride) {
    const float4 v = lp4[i];
    a0 += v.x * __expf(v.x);
    a1 += v.y * __expf(v.y);
    a2 += v.z * __expf(v.z);
    a3 += v.w * __expf(v.w);
  }
  float ent = (a0 + a1) + (a2 + a3);
  for (int off = 32; off > 0; off >>= 1) ent += __shfl_down(ent, off, 64);
  __shared__ float wsum[4];
  if ((tid & 63) == 0) wsum[tid >> 6] = ent;
  __syncthreads();
  if (tid == 0) ent_part[blockIdx.x] = wsum[0] + wsum[1] + wsum[2] + wsum[3];
}

// ---------------------------------------------------------------------------
// K2: CTC forward DP. One wave per batch element; states live in registers:
//   lane i holds e0 = alpha[2i] (blank), e1 = alpha[2i+1] (label i),
//   lane 63 additionally e2 = alpha[128] (final blank).
// Per t-step cross-lane traffic = ONE shfl_up (alpha[2i-1]). No LDS, no
// barriers. lp gathered directly (L3-resident after K1) with K-deep register
// prefetch: per t, blank = row[0] (same-addr broadcast) + label = row[cls].
// ---------------------------------------------------------------------------
__global__ __launch_bounds__(64) void k_ctc(
    const float* __restrict__ lp, const int* __restrict__ targets,
    const int* __restrict__ in_len, const int* __restrict__ tg_len,
    float* __restrict__ nll_out) {
  const int b = blockIdx.x;
  const int lane = threadIdx.x;  // 0..63
  const int len = in_len[b];     // in [512, 1024]
  const int tl = tg_len[b];      // in [32, 64]

  const int cls = targets[b * L + lane];  // label class for state 2*lane+1
  const int prevc = (lane == 0) ? -1 : targets[b * L + lane - 1];
  const bool allow2 = (cls != prevc);     // skip-transition mask (lane0: true)

  auto loadch = [&](int tstart, float (&bb)[K], float (&lv)[K]) {
#pragma unroll
    for (int k = 0; k < K; ++k) {
      const int t = tstart + k;
      const int tt = (t < len) ? t : (len - 1);  // clamp (values unused)
      const float* row = lp + ((size_t)tt * B + b) * C;
      bb[k] = row[0];    // blank log-prob (broadcast load)
      lv[k] = row[cls];  // this lane's label log-prob (scatter within 1 KiB)
    }
  };

  // t = 0 init: alpha0[0] = lp[0][b][blank], alpha0[1] = lp[0][b][target0]
  float e0, e1, e2;
  {
    const float* row0 = lp + (size_t)b * C;
    e0 = (lane == 0) ? row0[0] : NEG;
    e1 = (lane == 0) ? row0[cls] : NEG;
    e2 = NEG;
  }

  float cb[K], cl[K], nb[K] = {}, nl[K] = {};
  loadch(1, cb, cl);
  for (int tc = 1; tc < len; tc += K) {
    if (tc + K < len) loadch(tc + K, nb, nl);  // prefetch next chunk
#pragma unroll
    for (int k = 0; k < K; ++k) {
      if (tc + k >= len) break;  // uniform branch (len is block-scalar)
      const float lpb = cb[k], lpl = cl[k];
      float pe1 = __shfl_up(e1, 1, 64);  // alpha[2i-1] from lane i-1
      pe1 = (lane == 0) ? NEG : pe1;
      // state 128 (meaningful on lane 63 only): lse(a[128], a[127]) + lp_blank
      const float m2 = fmaxf(e2, e1);
      const float n2 = m2 + __logf(__expf(e2 - m2) + __expf(e1 - m2)) + lpb;
      // even state 2i (blank, no skip): lse(a[2i], a[2i-1]) + lp_blank
      const float m0 = fmaxf(e0, pe1);
      const float n0 = m0 + __logf(__expf(e0 - m0) + __expf(pe1 - m0)) + lpb;
      // odd state 2i+1 (label): lse(a[2i+1], a[2i], allow2 ? a[2i-1]) + lp_lab
      const float p2 = allow2 ? pe1 : NEG;
      const float m1 = fmaxf(e1, fmaxf(e0, p2));
      const float n1 =
          m1 + __logf(__expf(e1 - m1) + __expf(e0 - m1) + __expf(p2 - m1)) + lpl;
      e0 = n0; e1 = n1; e2 = n2;
    }
#pragma unroll
    for (int k = 0; k < K; ++k) { cb[k] = nb[k]; cl[k] = nl[k]; }
  }

  // ll = lse(alpha[2*tl], alpha[2*tl-1]) at t = len-1
  const float a1 = (tl == L) ? __shfl(e2, 63, 64) : __shfl(e0, tl, 64);
  const float a0 = __shfl(e1, tl - 1, 64);
  if (lane == 0) {
    const float m = fmaxf(a1, a0);
    const float ll = m + __logf(__expf(a1 - m) + __expf(a0 - m));
    float nll = -ll;
    if (nll > 1e29f) nll = 0.f;  // zero_infinity
    nll_out[b] = nll;
  }
}

// ---------------------------------------------------------------------------
// K3: combine 1024 entropy partials + 128 per-sample NLLs into the scalar.
// ---------------------------------------------------------------------------
__global__ __launch_bounds__(256) void k_final(
    const float* __restrict__ ent_part, const float* __restrict__ nll,
    float* __restrict__ out) {
  const int tid = threadIdx.x;
  float s = 0.f;
  for (int i = tid; i < ENT_GRID; i += 256) s += ent_part[i];
  float n = (tid < B) ? nll[tid] : 0.f;
  for (int off = 32; off > 0; off >>= 1) {
    s += __shfl_down(s, off, 64);
    n += __shfl_down(n, off, 64);
  }
  __shared__ float ss[4], nn[4];
  if ((tid & 63) == 0) { ss[tid >> 6] = s; nn[tid >> 6] = n; }
  __syncthreads();
  if (tid == 0) {
    const float ent_sum = ss[0] + ss[1] + ss[2] + ss[3];
    const float nll_sum = nn[0] + nn[1] + nn[2] + nn[3];
    const float ctc_mean = nll_sum / (float)B;
    const float smooth = ent_sum / (float)(T * B);  // = -entropy.mean()
    out[0] = 0.9f * ctc_mean + 0.1f * smooth;
  }
}

extern "C" void kernel_launch(void* const* d_in, const int* in_sizes, int n_in,
                              void* d_out, int out_size, void* d_ws, size_t ws_size,
                              hipStream_t stream) {
  const float* lp      = (const float*)d_in[0];  // [T,B,C] f32
  const int*   targets = (const int*)d_in[1];    // [B,L] i32
  const int*   in_len  = (const int*)d_in[2];    // [B] i32
  const int*   tg_len  = (const int*)d_in[3];    // [B] i32
  float* out = (float*)d_out;
  float* ws  = (float*)d_ws;

  float* ent_part = ws;             // [1024]
  float* nllb     = ws + ENT_GRID;  // [128]

  k_entropy<<<ENT_GRID, 256, 0, stream>>>(lp, ent_part);
  k_ctc<<<B, 64, 0, stream>>>(lp, targets, in_len, tg_len, nllb);
  k_final<<<1, 256, 0, stream>>>(ent_part, nllb, out);
}

// Round 3
// 383.698 us; speedup vs baseline: 1.2258x; 1.2258x over previous
//
#include <hip/hip_runtime.h>

// Problem constants (from reference): T=1024, B=128, C=256, L=64
#define NEG (-1e30f)
constexpr int T = 1024;
constexpr int B = 128;
constexpr int C = 256;
constexpr int L = 64;
constexpr int ENT_GRID = 1024;  // entropy blocks (blocks [0, ENT_GRID))
constexpr int CH = 16;          // t-steps per async-staged chunk
// per chunk: CH label-gather instrs + 1 blank instr = 17 vmem instructions.
// steady state 3 chunks in flight -> wait vmcnt(34) == oldest chunk landed.

__device__ __forceinline__ void gload_lds4(const float* g, float* l) {
  __builtin_amdgcn_global_load_lds(
      (const __attribute__((address_space(1))) void*)g,
      (__attribute__((address_space(3))) void*)l, 4, 0, 0);
}

// ---------------------------------------------------------------------------
// Fused kernel. Blocks [0,1024): entropy float4 stream -> per-block partial.
// Blocks [1024,1152): CTC forward DP, one wave per batch element.
//   - lp staged ahead via global_load_lds (async DMA, vmcnt-tracked): the
//     compiler CANNOT sink these to point-of-use (round-2 failure mode).
//   - alpha in registers: lane i holds states 2i (e0), 2i+1 (e1); lane 63
//     also state 128 (e2). Cross-lane dep = one DPP wave_shr:1 per step.
// ---------------------------------------------------------------------------
__global__ __launch_bounds__(256) void k_fused(
    const float* __restrict__ lp, const int* __restrict__ targets,
    const int* __restrict__ in_len, const int* __restrict__ tg_len,
    float* __restrict__ ent_part, float* __restrict__ nll_out) {
  __shared__ float lab[4][CH][64];  // ring of 4 chunks: label lp per (k, lane)
  __shared__ float blk[4][CH];      // blank lp per (chunk, k)
  __shared__ float wsum[4];
  const int tid = threadIdx.x;

  if (blockIdx.x < ENT_GRID) {
    // ---------------- entropy path ----------------
    const size_t N4 = (size_t)T * B * C / 4;
    const float4* lp4 = (const float4*)lp;
    const size_t stride = (size_t)ENT_GRID * 256;
    float a0 = 0.f, a1 = 0.f, a2 = 0.f, a3 = 0.f;
    for (size_t i = (size_t)blockIdx.x * 256 + tid; i < N4; i += stride) {
      const float4 v = lp4[i];
      a0 += v.x * __expf(v.x);
      a1 += v.y * __expf(v.y);
      a2 += v.z * __expf(v.z);
      a3 += v.w * __expf(v.w);
    }
    float ent = (a0 + a1) + (a2 + a3);
    for (int off = 32; off > 0; off >>= 1) ent += __shfl_down(ent, off, 64);
    if ((tid & 63) == 0) wsum[tid >> 6] = ent;
    __syncthreads();
    if (tid == 0) ent_part[blockIdx.x] = wsum[0] + wsum[1] + wsum[2] + wsum[3];
    return;
  }

  // ---------------- CTC path (wave 0 only) ----------------
  if (tid >= 64) return;
  const int b = blockIdx.x - ENT_GRID;
  const int lane = tid;
  const int len = in_len[b];  // in [512, 1024]
  const int tl = tg_len[b];   // in [32, 64]

  const int cls = targets[b * L + lane];
  const int prevc = (lane == 0) ? -1 : targets[b * L + lane - 1];
  const bool allow2 = (cls != prevc);
  const float* rowb = lp + (size_t)b * C;  // row(t) = rowb + t*B*C

  const int steps = len - 1;               // DP over t = 1..len-1
  const int nch = (steps + CH - 1) / CH;   // >= 32 always

  auto issue_chunk = [&](int c) {
    const int slot = c & 3;
    const int t0 = 1 + c * CH;
    for (int k = 0; k < CH; ++k) {
      int t = t0 + k;
      t = (t < len) ? t : (len - 1);  // clamp: valid addr, value unused
      gload_lds4(rowb + (size_t)t * (B * C) + cls, &lab[slot][k][0]);
    }
    if (lane < CH) {  // one exec-masked instr: CH blanks -> blk[slot][0..CH)
      int t = t0 + lane;
      t = (t < len) ? t : (len - 1);
      gload_lds4(rowb + (size_t)t * (B * C), &blk[slot][0]);
    }
  };

  // t = 0 init
  float e0 = NEG, e1 = NEG, e2 = NEG;
  if (lane == 0) {
    e0 = rowb[0];    // alpha0[0] = lp[0][b][blank]
    e1 = rowb[cls];  // alpha0[1] = lp[0][b][target0]
  }

  issue_chunk(0);
  issue_chunk(1);
  issue_chunk(2);
  for (int c = 0; c < nch; ++c) {
    // oldest in-flight chunk (c) has landed when <= 2*17 remain outstanding
    asm volatile("s_waitcnt vmcnt(34)" ::: "memory");
    issue_chunk(c + 3);  // clamped; overwrites slot (c-1)&3 (already consumed)
    const int slot = c & 3;
    const int kend = min(CH, steps - c * CH);
    for (int k = 0; k < kend; ++k) {
      const float lpl = lab[slot][k][lane];  // own label lp (2-way bank: free)
      const float lpbv = blk[slot][k];       // blank lp (broadcast)
      // alpha[2i-1] from lane i-1 via DPP wave_shr:1; lane0 gets old=NEG
      const float pe1 = __int_as_float(__builtin_amdgcn_update_dpp(
          __float_as_int(NEG), __float_as_int(e1), 0x138, 0xF, 0xF, false));
      // state 128 (lane 63): lse(a[128], a[127]) + lp_blank
      const float m2 = fmaxf(e2, e1);
      const float n2 = m2 + __logf(__expf(e2 - m2) + __expf(e1 - m2)) + lpbv;
      // even state 2i (blank): lse(a[2i], a[2i-1]) + lp_blank
      const float m0 = fmaxf(e0, pe1);
      const float n0 = m0 + __logf(__expf(e0 - m0) + __expf(pe1 - m0)) + lpbv;
      // odd state 2i+1 (label): lse(a[2i+1], a[2i], allow2? a[2i-1]) + lp_lab
      const float p2v = allow2 ? pe1 : NEG;
      const float m1 = fmaxf(e1, fmaxf(e0, p2v));
      const float n1 = m1 +
          __logf(__expf(e1 - m1) + __expf(e0 - m1) + __expf(p2v - m1)) + lpl;
      e0 = n0;
      e1 = n1;
      e2 = n2;
    }
  }
  // drain stragglers (over-issued tail chunks) before LDS dealloc / exit
  asm volatile("s_waitcnt vmcnt(0)" ::: "memory");

  // ll = lse(alpha[2*tl], alpha[2*tl-1]) at t = len-1
  const float a1 = (tl == L) ? __shfl(e2, 63, 64) : __shfl(e0, tl, 64);
  const float a0v = __shfl(e1, tl - 1, 64);
  if (lane == 0) {
    const float m = fmaxf(a1, a0v);
    const float ll = m + __logf(__expf(a1 - m) + __expf(a0v - m));
    float nll = -ll;
    if (nll > 1e29f) nll = 0.f;  // zero_infinity
    nll_out[b] = nll;
  }
}

// ---------------------------------------------------------------------------
// Final combine: 1024 entropy partials + 128 per-sample NLLs -> scalar loss.
// ---------------------------------------------------------------------------
__global__ __launch_bounds__(256) void k_final(
    const float* __restrict__ ent_part, const float* __restrict__ nll,
    float* __restrict__ out) {
  const int tid = threadIdx.x;
  float s = 0.f;
  for (int i = tid; i < ENT_GRID; i += 256) s += ent_part[i];
  float n = (tid < B) ? nll[tid] : 0.f;
  for (int off = 32; off > 0; off >>= 1) {
    s += __shfl_down(s, off, 64);
    n += __shfl_down(n, off, 64);
  }
  __shared__ float ss[4], nn[4];
  if ((tid & 63) == 0) { ss[tid >> 6] = s; nn[tid >> 6] = n; }
  __syncthreads();
  if (tid == 0) {
    const float ent_sum = ss[0] + ss[1] + ss[2] + ss[3];
    const float nll_sum = nn[0] + nn[1] + nn[2] + nn[3];
    const float ctc_mean = nll_sum / (float)B;
    const float smooth = ent_sum / (float)(T * B);  // = -entropy.mean()
    out[0] = 0.9f * ctc_mean + 0.1f * smooth;
  }
}

extern "C" void kernel_launch(void* const* d_in, const int* in_sizes, int n_in,
                              void* d_out, int out_size, void* d_ws, size_t ws_size,
                              hipStream_t stream) {
  const float* lp      = (const float*)d_in[0];  // [T,B,C] f32
  const int*   targets = (const int*)d_in[1];    // [B,L] i32
  const int*   in_len  = (const int*)d_in[2];    // [B] i32
  const int*   tg_len  = (const int*)d_in[3];    // [B] i32
  float* out = (float*)d_out;
  float* ws  = (float*)d_ws;

  float* ent_part = ws;             // [1024]
  float* nllb     = ws + ENT_GRID;  // [128]

  k_fused<<<ENT_GRID + B, 256, 0, stream>>>(lp, targets, in_len, tg_len,
                                            ent_part, nllb);
  k_final<<<1, 256, 0, stream>>>(ent_part, nllb, out);
}

// Round 5
// 260.513 us; speedup vs baseline: 1.8054x; 1.4729x over previous
//
#include <hip/hip_runtime.h>

// Problem constants (from reference): T=1024, B=128, C=256, L=64
#define NEG (-1e30f)
#define LOG2E 1.4426950408889634f
#define LN2 0.69314718055994531f
constexpr int T = 1024;
constexpr int B = 128;
constexpr int C = 256;
constexpr int L = 64;
constexpr int ENT_GRID = 1024;  // entropy blocks (blocks [0, ENT_GRID))
constexpr int K = 24;           // t-steps per register-staged chunk
// Per chunk: 24 label-gather loads + 1 blank load = 25 vmem instrs (all inline
// asm -> invisible to the compiler's waitcnt pass; we own the counts).
// Double buffer: <=50 in flight (< vmcnt cap 63). vmcnt retires IN ORDER, so
// "s_waitcnt vmcnt(25)" with 50 outstanding == oldest chunk fully landed.

// HW base-2 transcendentals (v_exp_f32 / v_log_f32 ARE base-2 on gfx9/CDNA).
// __exp2f/__log2f do NOT exist in HIP (round-4 build break) — guard + fallback.
#if __has_builtin(__builtin_amdgcn_exp2f)
__device__ __forceinline__ float fexp2(float x) { return __builtin_amdgcn_exp2f(x); }
#else
__device__ __forceinline__ float fexp2(float x) { return __expf(x * LN2); }
#endif
#if __has_builtin(__builtin_amdgcn_logf)
__device__ __forceinline__ float flog2(float x) { return __builtin_amdgcn_logf(x); }
#else
__device__ __forceinline__ float flog2(float x) { return __logf(x) * LOG2E; }
#endif

__device__ __forceinline__ float dpp_shr1(float x, float oldv) {
  // wave_shr:1 -- lane i gets lane i-1's x; lane 0 keeps `oldv`.
  return __int_as_float(__builtin_amdgcn_update_dpp(
      __float_as_int(oldv), __float_as_int(x), 0x138, 0xF, 0xF, false));
}

// Issue one chunk: per-lane label gather (t uniform per instr, cls per lane)
// plus one blank load (lane k -> blank(t0+k)). Byte offsets: t*B*C*4 = t<<17.
#define ISSUE(LA, BL, c_)                                                   \
  do {                                                                      \
    const int t0_ = 1 + (c_)*K;                                             \
    _Pragma("unroll") for (int k_ = 0; k_ < K; ++k_) {                      \
      const int t_ = min(t0_ + k_, lenm1); /* clamp: valid addr, unused */  \
      const unsigned off_ = labBase + ((unsigned)t_ << 17);                 \
      asm volatile("global_load_dword %0, %1, %2"                           \
                   : "=v"(LA[k_])                                           \
                   : "v"(off_), "s"(lp));                                   \
    }                                                                       \
    {                                                                       \
      const int tb_ = min(t0_ + lane, lenm1);                               \
      const unsigned offb_ = blkBase + ((unsigned)tb_ << 17);               \
      asm volatile("global_load_dword %0, %1, %2"                           \
                   : "=v"(BL)                                               \
                   : "v"(offb_), "s"(lp));                                  \
    }                                                                       \
  } while (0)

// Wait until only the newest 25 loads remain outstanding (oldest chunk done).
// "+v" ties REDEFINE the buffer registers so no use can be scheduled above.
#define WAITTIE(LA, BL)                                                     \
  asm volatile("s_waitcnt vmcnt(25)"                                        \
               : "+v"(LA[0]), "+v"(LA[1]), "+v"(LA[2]), "+v"(LA[3]),        \
                 "+v"(LA[4]), "+v"(LA[5]), "+v"(LA[6]), "+v"(LA[7]),        \
                 "+v"(LA[8]), "+v"(LA[9]), "+v"(LA[10]), "+v"(LA[11]),      \
                 "+v"(LA[12]), "+v"(LA[13]), "+v"(LA[14]), "+v"(LA[15]),    \
                 "+v"(LA[16]), "+v"(LA[17]), "+v"(LA[18]), "+v"(LA[19]),    \
                 "+v"(LA[20]), "+v"(LA[21]), "+v"(LA[22]), "+v"(LA[23]),    \
                 "+v"(BL))

// One chunk of DP steps, all in log2 domain, zero memory ops.
// State mapping: a0 = alpha[0] (wave-uniform); lane i: o = alpha[2i+1]
// (label i), v = alpha[2i+2] (blank). Recurrences:
//   a0' = a0 + lpb
//   o'  = lse(o, v@(i-1), [labels differ] o@(i-1)) + lpl_i   (lane0: v@-1=a0)
//   v'  = lse(v, o) + lpb                                     (all local)
#define COMPUTE(LA, BL, c_)                                                 \
  do {                                                                      \
    const float blsc_ = (BL)*LOG2E;                                         \
    const int kend_ = steps - (c_)*K;                                       \
    _Pragma("unroll") for (int k_ = 0; k_ < K; ++k_) {                      \
      if (k_ >= kend_) break; /* uniform */                                 \
      const float sb_ = __int_as_float(                                     \
          __builtin_amdgcn_readlane(__float_as_int(blsc_), k_));            \
      const float lw_ = LA[k_] * LOG2E;                                     \
      const float ev2_ = dpp_shr1(v, a0);   /* alpha[2i] */                 \
      const float od2_ = dpp_shr1(o, NEG);  /* alpha[2i-1] */               \
      const float p2_ = sameAsPrev ? NEG : od2_;                            \
      const float m1_ = fmaxf(o, fmaxf(ev2_, p2_));                         \
      const float s1_ =                                                     \
          fexp2(o - m1_) + fexp2(ev2_ - m1_) + fexp2(p2_ - m1_);            \
      const float no_ = m1_ + flog2(s1_) + lw_;                             \
      const float m0_ = fmaxf(v, o);                                        \
      const float s0_ = fexp2(v - m0_) + fexp2(o - m0_);                    \
      const float nv_ = m0_ + flog2(s0_) + sb_;                             \
      a0 += sb_;                                                            \
      o = no_;                                                              \
      v = nv_;                                                              \
    }                                                                       \
  } while (0)

// ---------------------------------------------------------------------------
// Fused kernel. Blocks [0,1024): entropy float4 stream -> per-block partial.
// Blocks [1024,1152): CTC forward DP, one wave per batch element, register-
// resident alpha, inline-asm load pipeline, pure-VALU inner loop.
// ---------------------------------------------------------------------------
__global__ __launch_bounds__(256) void k_fused(
    const float* __restrict__ lp, const int* __restrict__ targets,
    const int* __restrict__ in_len, const int* __restrict__ tg_len,
    float* __restrict__ ent_part, float* __restrict__ nll_out) {
  __shared__ float wsum[4];
  const int tid = threadIdx.x;

  if (blockIdx.x < ENT_GRID) {
    // ---------------- entropy path ----------------
    const size_t N4 = (size_t)T * B * C / 4;
    const float4* lp4 = (const float4*)lp;
    const size_t stride = (size_t)ENT_GRID * 256;
    float a0 = 0.f, a1 = 0.f, a2 = 0.f, a3 = 0.f;
    for (size_t i = (size_t)blockIdx.x * 256 + tid; i < N4; i += stride) {
      const float4 vv = lp4[i];
      a0 += vv.x * __expf(vv.x);
      a1 += vv.y * __expf(vv.y);
      a2 += vv.z * __expf(vv.z);
      a3 += vv.w * __expf(vv.w);
    }
    float ent = (a0 + a1) + (a2 + a3);
    for (int off = 32; off > 0; off >>= 1) ent += __shfl_down(ent, off, 64);
    if ((tid & 63) == 0) wsum[tid >> 6] = ent;
    __syncthreads();
    if (tid == 0) ent_part[blockIdx.x] = wsum[0] + wsum[1] + wsum[2] + wsum[3];
    return;
  }

  // ---------------- CTC path (wave 0 only) ----------------
  if (tid >= 64) return;
  const int b = blockIdx.x - ENT_GRID;
  const int lane = tid;
  const int len = in_len[b];  // in [512, 1024]
  const int tl = tg_len[b];   // in [32, 64]
  const int lenm1 = len - 1;
  const int steps = lenm1;    // DP over t = 1..len-1
  const int nch = (steps + K - 1) / K;  // >= 22 (len >= 512)

  const int cls = targets[b * L + lane];  // label for odd state 2*lane+1
  const int prevc = (lane == 0) ? -1 : targets[b * L + lane - 1];
  const bool sameAsPrev = (cls == prevc);  // skip-transition blocked
  const unsigned labBase = ((unsigned)b << 10) + ((unsigned)cls << 2);
  const unsigned blkBase = ((unsigned)b << 10);

  // t = 0 init (compiler-visible loads; drained before the asm pipeline)
  const float lpb0 = lp[(size_t)b * C];
  const float lpl0 = lp[(size_t)b * C + cls];
  float a0 = lpb0 * LOG2E;                        // alpha[0]
  float o = (lane == 0) ? lpl0 * LOG2E : NEG;     // alpha[2i+1]
  float v = NEG;                                  // alpha[2i+2]

  // From here on, manual vmcnt bookkeeping: start from a clean slate.
  asm volatile("s_waitcnt vmcnt(0) lgkmcnt(0)" ::: "memory");

  float laA[K], laB[K], blA, blB;
  ISSUE(laA, blA, 0);  // 25 in flight
  int c = 0;
  for (;;) {
    ISSUE(laB, blB, c + 1);  // 50 in flight
    WAITTIE(laA, blA);       // chunk c landed
    COMPUTE(laA, blA, c);
    ++c;
    if (c == nch) break;
    ISSUE(laA, blA, c + 1);
    WAITTIE(laB, blB);
    COMPUTE(laB, blB, c);
    ++c;
    if (c == nch) break;
  }
  asm volatile("s_waitcnt vmcnt(0)" ::: "memory");  // drain over-issued tail

  // ll = lse(alpha[2*tl], alpha[2*tl-1]) at t=len-1; both live at lane tl-1.
  const float aE = __shfl(v, tl - 1, 64);  // alpha[2*tl]
  const float aO = __shfl(o, tl - 1, 64);  // alpha[2*tl-1]
  if (lane == 0) {
    const float m = fmaxf(aE, aO);
    const float ll = (m + flog2(fexp2(aE - m) + fexp2(aO - m))) * LN2;
    float nll = -ll;
    if (nll > 1e29f) nll = 0.f;  // zero_infinity
    nll_out[b] = nll;
  }
}

// ---------------------------------------------------------------------------
// Final combine: 1024 entropy partials + 128 per-sample NLLs -> scalar loss.
// ---------------------------------------------------------------------------
__global__ __launch_bounds__(256) void k_final(
    const float* __restrict__ ent_part, const float* __restrict__ nll,
    float* __restrict__ out) {
  const int tid = threadIdx.x;
  float s = 0.f;
  for (int i = tid; i < ENT_GRID; i += 256) s += ent_part[i];
  float n = (tid < B) ? nll[tid] : 0.f;
  for (int off = 32; off > 0; off >>= 1) {
    s += __shfl_down(s, off, 64);
    n += __shfl_down(n, off, 64);
  }
  __shared__ float ss[4], nn[4];
  if ((tid & 63) == 0) { ss[tid >> 6] = s; nn[tid >> 6] = n; }
  __syncthreads();
  if (tid == 0) {
    const float ent_sum = ss[0] + ss[1] + ss[2] + ss[3];
    const float nll_sum = nn[0] + nn[1] + nn[2] + nn[3];
    const float ctc_mean = nll_sum / (float)B;
    const float smooth = ent_sum / (float)(T * B);  // = -entropy.mean()
    out[0] = 0.9f * ctc_mean + 0.1f * smooth;
  }
}

extern "C" void kernel_launch(void* const* d_in, const int* in_sizes, int n_in,
                              void* d_out, int out_size, void* d_ws, size_t ws_size,
                              hipStream_t stream) {
  const float* lp      = (const float*)d_in[0];  // [T,B,C] f32
  const int*   targets = (const int*)d_in[1];    // [B,L] i32
  const int*   in_len  = (const int*)d_in[2];    // [B] i32
  const int*   tg_len  = (const int*)d_in[3];    // [B] i32
  float* out = (float*)d_out;
  float* ws  = (float*)d_ws;

  float* ent_part = ws;             // [1024]
  float* nllb     = ws + ENT_GRID;  // [128]

  k_fused<<<ENT_GRID + B, 256, 0, stream>>>(lp, targets, in_len, tg_len,
                                            ent_part, nllb);
  k_final<<<1, 256, 0, stream>>>(ent_part, nllb, out);
}

// Round 6
// 259.875 us; speedup vs baseline: 1.8098x; 1.0025x over previous
//
#include <hip/hip_runtime.h>

// Problem constants (from reference): T=1024, B=128, C=256, L=64
#define NEG (-1e30f)
#define LOG2E 1.4426950408889634f
#define LN2 0.69314718055994531f
constexpr int T = 1024;
constexpr int B = 128;
constexpr int C = 256;
constexpr int L = 64;
constexpr int ENT_GRID = 1024;  // entropy blocks (blocks [0, ENT_GRID))
constexpr int K = 16;           // t-steps per register-staged chunk
// Per chunk: 16 label-gather loads + 1 blank load = 17 vmem instrs (all inline
// asm -> invisible to the compiler's waitcnt pass; we own the counts).
// Double buffer: <=34 in flight (< vmcnt cap 63). vmcnt retires IN ORDER, so
// "s_waitcnt vmcnt(17)" with 34 outstanding == oldest chunk fully landed.
// R5 lesson: without __launch_bounds__(...,1) the allocator spilled the
// staging arrays to scratch (WRITE_SIZE 36MB, VGPR=32, 274 cy/step).

// HW base-2 transcendentals (v_exp_f32 / v_log_f32 ARE base-2 on CDNA).
#if __has_builtin(__builtin_amdgcn_exp2f)
__device__ __forceinline__ float fexp2(float x) { return __builtin_amdgcn_exp2f(x); }
#else
__device__ __forceinline__ float fexp2(float x) { return __expf(x * LN2); }
#endif
#if __has_builtin(__builtin_amdgcn_logf)
__device__ __forceinline__ float flog2(float x) { return __builtin_amdgcn_logf(x); }
#else
__device__ __forceinline__ float flog2(float x) { return __logf(x) * LOG2E; }
#endif

__device__ __forceinline__ float dpp_shr1(float x, float oldv) {
  // wave_shr:1 -- lane i gets lane i-1's x; lane 0 keeps `oldv`.
  return __int_as_float(__builtin_amdgcn_update_dpp(
      __float_as_int(oldv), __float_as_int(x), 0x138, 0xF, 0xF, false));
}

// Issue one chunk: per-lane label gather (t uniform per instr, cls per lane)
// plus one blank load (lane k -> blank(t0+k)). Byte offsets: t*B*C*4 = t<<17.
#define ISSUE(LA, BL, c_)                                                   \
  do {                                                                      \
    const int t0_ = 1 + (c_)*K;                                             \
    _Pragma("unroll") for (int k_ = 0; k_ < K; ++k_) {                      \
      const int t_ = min(t0_ + k_, lenm1); /* clamp: valid addr, unused */  \
      const unsigned off_ = labBase + ((unsigned)t_ << 17);                 \
      asm volatile("global_load_dword %0, %1, %2"                           \
                   : "=v"(LA[k_])                                           \
                   : "v"(off_), "s"(lp));                                   \
    }                                                                       \
    {                                                                       \
      const int tb_ = min(t0_ + lane, lenm1);                               \
      const unsigned offb_ = blkBase + ((unsigned)tb_ << 17);               \
      asm volatile("global_load_dword %0, %1, %2"                           \
                   : "=v"(BL)                                               \
                   : "v"(offb_), "s"(lp));                                  \
    }                                                                       \
  } while (0)

// Wait until only the newest 17 loads remain outstanding (oldest chunk done).
// "+v" ties REDEFINE the buffer registers so no use can be scheduled above.
#define WAITTIE(LA, BL)                                                     \
  asm volatile("s_waitcnt vmcnt(17)"                                        \
               : "+v"(LA[0]), "+v"(LA[1]), "+v"(LA[2]), "+v"(LA[3]),        \
                 "+v"(LA[4]), "+v"(LA[5]), "+v"(LA[6]), "+v"(LA[7]),        \
                 "+v"(LA[8]), "+v"(LA[9]), "+v"(LA[10]), "+v"(LA[11]),      \
                 "+v"(LA[12]), "+v"(LA[13]), "+v"(LA[14]), "+v"(LA[15]),    \
                 "+v"(BL))

// One chunk of DP steps, all in log2 domain, zero memory ops.
// State mapping: a0 = alpha[0] (wave-uniform); lane i: o = alpha[2i+1]
// (label i), v = alpha[2i+2] (blank). Recurrences:
//   a0' = a0 + lpb
//   o'  = lse(o, v@(i-1), [labels differ] o@(i-1)) + lpl_i   (lane0: v@-1=a0)
//   v'  = lse(v, o) + lpb                                     (all local)
#define COMPUTE(LA, BL, c_)                                                 \
  do {                                                                      \
    const float blsc_ = (BL)*LOG2E;                                         \
    const int kend_ = steps - (c_)*K;                                       \
    _Pragma("unroll") for (int k_ = 0; k_ < K; ++k_) {                      \
      if (k_ >= kend_) break; /* uniform */                                 \
      const float sb_ = __int_as_float(                                     \
          __builtin_amdgcn_readlane(__float_as_int(blsc_), k_));            \
      const float lw_ = LA[k_] * LOG2E;                                     \
      const float ev2_ = dpp_shr1(v, a0);   /* alpha[2i] */                 \
      const float od2_ = dpp_shr1(o, NEG);  /* alpha[2i-1] */               \
      const float p2_ = sameAsPrev ? NEG : od2_;                            \
      const float m1_ = fmaxf(o, fmaxf(ev2_, p2_));                         \
      const float s1_ =                                                     \
          fexp2(o - m1_) + fexp2(ev2_ - m1_) + fexp2(p2_ - m1_);            \
      const float no_ = m1_ + flog2(s1_) + lw_;                             \
      const float m0_ = fmaxf(v, o);                                        \
      const float s0_ = fexp2(v - m0_) + fexp2(o - m0_);                    \
      const float nv_ = m0_ + flog2(s0_) + sb_;                             \
      a0 += sb_;                                                            \
      o = no_;                                                              \
      v = nv_;                                                              \
    }                                                                       \
  } while (0)

// ---------------------------------------------------------------------------
// Fused kernel. Blocks [0,1024): entropy float4 stream -> per-block partial.
// Blocks [1024,1152): CTC forward DP, one wave per batch element, register-
// resident alpha, inline-asm load pipeline, pure-VALU inner loop.
// __launch_bounds__(256, 1): min 1 wave/EU -> VGPR cap 512, so the staging
// buffers stay register-resident (R5: default budget spilled them).
// ---------------------------------------------------------------------------
__global__ __launch_bounds__(256, 1) void k_fused(
    const float* __restrict__ lp, const int* __restrict__ targets,
    const int* __restrict__ in_len, const int* __restrict__ tg_len,
    float* __restrict__ ent_part, float* __restrict__ nll_out) {
  __shared__ float wsum[4];
  const int tid = threadIdx.x;

  if (blockIdx.x < ENT_GRID) {
    // ---------------- entropy path ----------------
    const size_t N4 = (size_t)T * B * C / 4;
    const float4* lp4 = (const float4*)lp;
    const size_t stride = (size_t)ENT_GRID * 256;
    float a0 = 0.f, a1 = 0.f, a2 = 0.f, a3 = 0.f;
    for (size_t i = (size_t)blockIdx.x * 256 + tid; i < N4; i += stride) {
      const float4 vv = lp4[i];
      a0 += vv.x * __expf(vv.x);
      a1 += vv.y * __expf(vv.y);
      a2 += vv.z * __expf(vv.z);
      a3 += vv.w * __expf(vv.w);
    }
    float ent = (a0 + a1) + (a2 + a3);
    for (int off = 32; off > 0; off >>= 1) ent += __shfl_down(ent, off, 64);
    if ((tid & 63) == 0) wsum[tid >> 6] = ent;
    __syncthreads();
    if (tid == 0) ent_part[blockIdx.x] = wsum[0] + wsum[1] + wsum[2] + wsum[3];
    return;
  }

  // ---------------- CTC path (wave 0 only) ----------------
  if (tid >= 64) return;
  const int b = blockIdx.x - ENT_GRID;
  const int lane = tid;
  const int len = in_len[b];  // in [512, 1024]
  const int tl = tg_len[b];   // in [32, 64]
  const int lenm1 = len - 1;
  const int steps = lenm1;    // DP over t = 1..len-1
  const int nch = (steps + K - 1) / K;

  const int cls = targets[b * L + lane];  // label for odd state 2*lane+1
  const int prevc = (lane == 0) ? -1 : targets[b * L + lane - 1];
  const bool sameAsPrev = (cls == prevc);  // skip-transition blocked
  const unsigned labBase = ((unsigned)b << 10) + ((unsigned)cls << 2);
  const unsigned blkBase = ((unsigned)b << 10);

  // t = 0 init (compiler-visible loads; drained before the asm pipeline)
  const float lpb0 = lp[(size_t)b * C];
  const float lpl0 = lp[(size_t)b * C + cls];
  float a0 = lpb0 * LOG2E;                        // alpha[0]
  float o = (lane == 0) ? lpl0 * LOG2E : NEG;     // alpha[2i+1]
  float v = NEG;                                  // alpha[2i+2]

  // From here on, manual vmcnt bookkeeping: start from a clean slate.
  asm volatile("s_waitcnt vmcnt(0) lgkmcnt(0)" ::: "memory");

  float laA[K], laB[K], blA, blB;
  ISSUE(laA, blA, 0);  // 17 in flight
  int c = 0;
  for (;;) {
    ISSUE(laB, blB, c + 1);  // 34 in flight
    WAITTIE(laA, blA);       // chunk c landed
    COMPUTE(laA, blA, c);
    ++c;
    if (c == nch) break;
    ISSUE(laA, blA, c + 1);
    WAITTIE(laB, blB);
    COMPUTE(laB, blB, c);
    ++c;
    if (c == nch) break;
  }
  asm volatile("s_waitcnt vmcnt(0)" ::: "memory");  // drain over-issued tail

  // ll = lse(alpha[2*tl], alpha[2*tl-1]) at t=len-1; both live at lane tl-1.
  const float aE = __shfl(v, tl - 1, 64);  // alpha[2*tl]
  const float aO = __shfl(o, tl - 1, 64);  // alpha[2*tl-1]
  if (lane == 0) {
    const float m = fmaxf(aE, aO);
    const float ll = (m + flog2(fexp2(aE - m) + fexp2(aO - m))) * LN2;
    float nll = -ll;
    if (nll > 1e29f) nll = 0.f;  // zero_infinity
    nll_out[b] = nll;
  }
}

// ---------------------------------------------------------------------------
// Final combine: 1024 entropy partials + 128 per-sample NLLs -> scalar loss.
// ---------------------------------------------------------------------------
__global__ __launch_bounds__(256) void k_final(
    const float* __restrict__ ent_part, const float* __restrict__ nll,
    float* __restrict__ out) {
  const int tid = threadIdx.x;
  float s = 0.f;
  for (int i = tid; i < ENT_GRID; i += 256) s += ent_part[i];
  float n = (tid < B) ? nll[tid] : 0.f;
  for (int off = 32; off > 0; off >>= 1) {
    s += __shfl_down(s, off, 64);
    n += __shfl_down(n, off, 64);
  }
  __shared__ float ss[4], nn[4];
  if ((tid & 63) == 0) { ss[tid >> 6] = s; nn[tid >> 6] = n; }
  __syncthreads();
  if (tid == 0) {
    const float ent_sum = ss[0] + ss[1] + ss[2] + ss[3];
    const float nll_sum = nn[0] + nn[1] + nn[2] + nn[3];
    const float ctc_mean = nll_sum / (float)B;
    const float smooth = ent_sum / (float)(T * B);  // = -entropy.mean()
    out[0] = 0.9f * ctc_mean + 0.1f * smooth;
  }
}

extern "C" void kernel_launch(void* const* d_in, const int* in_sizes, int n_in,
                              void* d_out, int out_size, void* d_ws, size_t ws_size,
                              hipStream_t stream) {
  const float* lp      = (const float*)d_in[0];  // [T,B,C] f32
  const int*   targets = (const int*)d_in[1];    // [B,L] i32
  const int*   in_len  = (const int*)d_in[2];    // [B] i32
  const int*   tg_len  = (const int*)d_in[3];    // [B] i32
  float* out = (float*)d_out;
  float* ws  = (float*)d_ws;

  float* ent_part = ws;             // [1024]
  float* nllb     = ws + ENT_GRID;  // [128]

  k_fused<<<ENT_GRID + B, 256, 0, stream>>>(lp, targets, in_len, tg_len,
                                            ent_part, nllb);
  k_final<<<1, 256, 0, stream>>>(ent_part, nllb, out);
}

// Round 7
// 240.515 us; speedup vs baseline: 1.9555x; 1.0805x over previous
//
#include <hip/hip_runtime.h>

// Problem constants (from reference): T=1024, B=128, C=256, L=64
#define NEG (-1e30f)
#define LOG2E 1.4426950408889634f
#define LN2 0.69314718055994531f
constexpr int T = 1024;
constexpr int B = 128;
constexpr int C = 256;
constexpr int L = 64;
constexpr int ENT_GRID = 1024;  // entropy blocks (blocks [0, ENT_GRID))
constexpr int K = 16;           // t-steps per register-staged chunk
// Per chunk: 16 label-gather loads + 1 blank load = 17 vmem instrs (inline
// asm -> invisible to the compiler's waitcnt pass; we own the counts).
// Double buffer: <=34 in flight. vmcnt retires IN ORDER, so
// "s_waitcnt vmcnt(17)" with 34 outstanding == oldest chunk fully landed.
// R5/R6 lesson: float arrays are allocas; SROA runs BEFORE unroll, sees
// variable indices, never promotes -> every load bounced through scratch
// (WRITE_SIZE 36MB). Fix: individually NAMED scalars via macros. No alloca.

// HW base-2 transcendentals (v_exp_f32 / v_log_f32 ARE base-2 on CDNA).
#if __has_builtin(__builtin_amdgcn_exp2f)
__device__ __forceinline__ float fexp2(float x) { return __builtin_amdgcn_exp2f(x); }
#else
__device__ __forceinline__ float fexp2(float x) { return __expf(x * LN2); }
#endif
#if __has_builtin(__builtin_amdgcn_logf)
__device__ __forceinline__ float flog2(float x) { return __builtin_amdgcn_logf(x); }
#else
__device__ __forceinline__ float flog2(float x) { return __logf(x) * LOG2E; }
#endif

__device__ __forceinline__ float dpp_shr1(float x, float oldv) {
  // wave_shr:1 -- lane i gets lane i-1's x; lane 0 keeps `oldv`.
  return __int_as_float(__builtin_amdgcn_update_dpp(
      __float_as_int(oldv), __float_as_int(x), 0x138, 0xF, 0xF, false));
}

// 2x17 staging registers as NAMED scalars (P in {A,B}): P0..P15 labels, Pb blank.
#define DECL17(P)                                                           \
  float P##0, P##1, P##2, P##3, P##4, P##5, P##6, P##7, P##8, P##9, P##10,  \
      P##11, P##12, P##13, P##14, P##15, P##b;

// One label-gather load: t uniform per instr, class column per lane.
// Byte offset: b*C*4 + cls*4 + t*B*C*4 = labBase + (t<<17).
#define LOAD1(P, c_, k_)                                                    \
  {                                                                         \
    const int t_ = min(1 + (c_)*K + k_, lenm1); /* clamp: addr ok, unused */\
    const unsigned off_ = labBase + ((unsigned)t_ << 17);                   \
    asm volatile("global_load_dword %0, %1, %2"                             \
                 : "=v"(P##k_)                                              \
                 : "v"(off_), "s"(lp));                                     \
  }

#define ISSUE(P, c_)                                                        \
  do {                                                                      \
    LOAD1(P, c_, 0) LOAD1(P, c_, 1) LOAD1(P, c_, 2) LOAD1(P, c_, 3)         \
    LOAD1(P, c_, 4) LOAD1(P, c_, 5) LOAD1(P, c_, 6) LOAD1(P, c_, 7)         \
    LOAD1(P, c_, 8) LOAD1(P, c_, 9) LOAD1(P, c_, 10) LOAD1(P, c_, 11)       \
    LOAD1(P, c_, 12) LOAD1(P, c_, 13) LOAD1(P, c_, 14) LOAD1(P, c_, 15)     \
    {                                                                       \
      const int tb_ = min(1 + (c_)*K + lane, lenm1);                        \
      const unsigned offb_ = blkBase + ((unsigned)tb_ << 17);               \
      asm volatile("global_load_dword %0, %1, %2"                           \
                   : "=v"(P##b)                                             \
                   : "v"(offb_), "s"(lp));                                  \
    }                                                                       \
  } while (0)

// Wait until only the newest 17 loads remain outstanding (oldest chunk done).
// "+v" ties REDEFINE the staging registers so no use can float above the wait.
#define WAITTIE(P)                                                          \
  asm volatile("s_waitcnt vmcnt(17)"                                        \
               : "+v"(P##0), "+v"(P##1), "+v"(P##2), "+v"(P##3),            \
                 "+v"(P##4), "+v"(P##5), "+v"(P##6), "+v"(P##7),            \
                 "+v"(P##8), "+v"(P##9), "+v"(P##10), "+v"(P##11),          \
                 "+v"(P##12), "+v"(P##13), "+v"(P##14), "+v"(P##15),        \
                 "+v"(P##b))

// One DP step (log2 domain, zero memory ops). State: a0 = alpha[0] (uniform);
// lane i: o = alpha[2i+1] (label i), v = alpha[2i+2] (blank).
//   a0' = a0 + lpb
//   o'  = lse(o, v@(i-1), [labels differ] o@(i-1)) + lpl_i  (lane0: v@-1=a0)
//   v'  = lse(v, o) + lpb                                    (all local)
#define STEP(P, k_)                                                         \
  if (k_ < kend_) {                                                         \
    const float sb_ = __int_as_float(                                       \
        __builtin_amdgcn_readlane(__float_as_int(blsc_), k_));              \
    const float lw_ = P##k_ * LOG2E;                                        \
    const float ev2_ = dpp_shr1(v, a0);  /* alpha[2i] */                    \
    const float od2_ = dpp_shr1(o, NEG); /* alpha[2i-1] */                  \
    const float p2_ = sameAsPrev ? NEG : od2_;                              \
    const float m1_ = fmaxf(o, fmaxf(ev2_, p2_));                           \
    const float s1_ =                                                       \
        fexp2(o - m1_) + fexp2(ev2_ - m1_) + fexp2(p2_ - m1_);              \
    const float no_ = m1_ + flog2(s1_) + lw_;                               \
    const float m0_ = fmaxf(v, o);                                          \
    const float s0_ = fexp2(v - m0_) + fexp2(o - m0_);                      \
    const float nv_ = m0_ + flog2(s0_) + sb_;                               \
    a0 += sb_;                                                              \
    o = no_;                                                                \
    v = nv_;                                                                \
  }

#define COMPUTE(P, c_)                                                      \
  do {                                                                      \
    const float blsc_ = (P##b)*LOG2E;                                       \
    const int kend_ = steps - (c_)*K;                                       \
    STEP(P, 0) STEP(P, 1) STEP(P, 2) STEP(P, 3) STEP(P, 4) STEP(P, 5)       \
    STEP(P, 6) STEP(P, 7) STEP(P, 8) STEP(P, 9) STEP(P, 10) STEP(P, 11)     \
    STEP(P, 12) STEP(P, 13) STEP(P, 14) STEP(P, 15)                         \
  } while (0)

// ---------------------------------------------------------------------------
// Fused kernel. Blocks [0,1024): entropy float4 stream -> per-block partial.
// Blocks [1024,1152): CTC forward DP, one wave per batch element, register-
// resident alpha + staging, inline-asm load pipeline, pure-VALU inner loop.
// ---------------------------------------------------------------------------
__global__ __launch_bounds__(256, 1) void k_fused(
    const float* __restrict__ lp, const int* __restrict__ targets,
    const int* __restrict__ in_len, const int* __restrict__ tg_len,
    float* __restrict__ ent_part, float* __restrict__ nll_out) {
  __shared__ float wsum[4];
  const int tid = threadIdx.x;

  if (blockIdx.x < ENT_GRID) {
    // ---------------- entropy path ----------------
    const size_t N4 = (size_t)T * B * C / 4;
    const float4* lp4 = (const float4*)lp;
    const size_t stride = (size_t)ENT_GRID * 256;
    float a0 = 0.f, a1 = 0.f, a2 = 0.f, a3 = 0.f;
    for (size_t i = (size_t)blockIdx.x * 256 + tid; i < N4; i += stride) {
      const float4 vv = lp4[i];
      a0 += vv.x * __expf(vv.x);
      a1 += vv.y * __expf(vv.y);
      a2 += vv.z * __expf(vv.z);
      a3 += vv.w * __expf(vv.w);
    }
    float ent = (a0 + a1) + (a2 + a3);
    for (int off = 32; off > 0; off >>= 1) ent += __shfl_down(ent, off, 64);
    if ((tid & 63) == 0) wsum[tid >> 6] = ent;
    __syncthreads();
    if (tid == 0) ent_part[blockIdx.x] = wsum[0] + wsum[1] + wsum[2] + wsum[3];
    return;
  }

  // ---------------- CTC path (wave 0 only) ----------------
  if (tid >= 64) return;
  const int b = blockIdx.x - ENT_GRID;
  const int lane = tid;
  const int len = in_len[b];  // in [512, 1024]
  const int tl = tg_len[b];   // in [32, 64]
  const int lenm1 = len - 1;
  const int steps = lenm1;    // DP over t = 1..len-1
  const int nch = (steps + K - 1) / K;

  const int cls = targets[b * L + lane];  // label for odd state 2*lane+1
  const int prevc = (lane == 0) ? -1 : targets[b * L + lane - 1];
  const bool sameAsPrev = (cls == prevc);  // skip-transition blocked
  const unsigned labBase = ((unsigned)b << 10) + ((unsigned)cls << 2);
  const unsigned blkBase = ((unsigned)b << 10);

  // t = 0 init (compiler-visible loads; drained before the asm pipeline)
  const float lpb0 = lp[(size_t)b * C];
  const float lpl0 = lp[(size_t)b * C + cls];
  float a0 = lpb0 * LOG2E;                     // alpha[0]
  float o = (lane == 0) ? lpl0 * LOG2E : NEG;  // alpha[2i+1]
  float v = NEG;                               // alpha[2i+2]

  // From here on, manual vmcnt bookkeeping: start from a clean slate.
  asm volatile("s_waitcnt vmcnt(0) lgkmcnt(0)" ::: "memory");

  DECL17(A)
  DECL17(B)
  ISSUE(A, 0);  // 17 in flight
  int c = 0;
  for (;;) {
    ISSUE(B, c + 1);  // 34 in flight
    WAITTIE(A);       // chunk c landed
    COMPUTE(A, c);
    ++c;
    if (c == nch) break;
    ISSUE(A, c + 1);
    WAITTIE(B);
    COMPUTE(B, c);
    ++c;
    if (c == nch) break;
  }
  asm volatile("s_waitcnt vmcnt(0)" ::: "memory");  // drain over-issued tail

  // ll = lse(alpha[2*tl], alpha[2*tl-1]) at t=len-1; both live at lane tl-1.
  const float aE = __shfl(v, tl - 1, 64);  // alpha[2*tl]
  const float aO = __shfl(o, tl - 1, 64);  // alpha[2*tl-1]
  if (lane == 0) {
    const float m = fmaxf(aE, aO);
    const float ll = (m + flog2(fexp2(aE - m) + fexp2(aO - m))) * LN2;
    float nll = -ll;
    if (nll > 1e29f) nll = 0.f;  // zero_infinity
    nll_out[b] = nll;
  }
}

// ---------------------------------------------------------------------------
// Final combine: 1024 entropy partials + 128 per-sample NLLs -> scalar loss.
// ---------------------------------------------------------------------------
__global__ __launch_bounds__(256) void k_final(
    const float* __restrict__ ent_part, const float* __restrict__ nll,
    float* __restrict__ out) {
  const int tid = threadIdx.x;
  float s = 0.f;
  for (int i = tid; i < ENT_GRID; i += 256) s += ent_part[i];
  float n = (tid < B) ? nll[tid] : 0.f;
  for (int off = 32; off > 0; off >>= 1) {
    s += __shfl_down(s, off, 64);
    n += __shfl_down(n, off, 64);
  }
  __shared__ float ss[4], nn[4];
  if ((tid & 63) == 0) { ss[tid >> 6] = s; nn[tid >> 6] = n; }
  __syncthreads();
  if (tid == 0) {
    const float ent_sum = ss[0] + ss[1] + ss[2] + ss[3];
    const float nll_sum = nn[0] + nn[1] + nn[2] + nn[3];
    const float ctc_mean = nll_sum / (float)B;
    const float smooth = ent_sum / (float)(T * B);  // = -entropy.mean()
    out[0] = 0.9f * ctc_mean + 0.1f * smooth;
  }
}

extern "C" void kernel_launch(void* const* d_in, const int* in_sizes, int n_in,
                              void* d_out, int out_size, void* d_ws, size_t ws_size,
                              hipStream_t stream) {
  const float* lp      = (const float*)d_in[0];  // [T,B,C] f32
  const int*   targets = (const int*)d_in[1];    // [B,L] i32
  const int*   in_len  = (const int*)d_in[2];    // [B] i32
  const int*   tg_len  = (const int*)d_in[3];    // [B] i32
  float* out = (float*)d_out;
  float* ws  = (float*)d_ws;

  float* ent_part = ws;             // [1024]
  float* nllb     = ws + ENT_GRID;  // [128]

  k_fused<<<ENT_GRID + B, 256, 0, stream>>>(lp, targets, in_len, tg_len,
                                            ent_part, nllb);
  k_final<<<1, 256, 0, stream>>>(ent_part, nllb, out);
}

// Round 8
// 211.295 us; speedup vs baseline: 2.2259x; 1.1383x over previous
//
#include <hip/hip_runtime.h>

// Problem constants (from reference): T=1024, B=128, C=256, L=64
#define NEG (-1e30f)
#define LOG2E 1.4426950408889634f
#define LN2 0.69314718055994531f
constexpr int T = 1024;
constexpr int B = 128;
constexpr int C = 256;
constexpr int L = 64;
constexpr int ENT_GRID = 1024;  // entropy blocks (blocks [0, ENT_GRID))
constexpr int K = 16;           // t-steps per register-staged chunk
// Forward-backward split: ll = lse_s(alpha_m[s] + beta_m[s] - lp_m[s]) at any
// m. Wave0: alpha t=1..m; Wave1: beta t=len-2..m. Serial length halves
// (1023 -> <=512). Staging: 17 named-scalar regs/chunk, double-buffered,
// inline-asm loads + owned s_waitcnt vmcnt(17) (R7 structure, proven exact).
// NOTE (R7 errata): WRITE_SIZE~36MB is harness-restore L2 writeback, NOT
// spill (constant across R3 LDS / R5 K=24 / R7 K=16; absent on non-first
// dispatches in R1/R2).

#if __has_builtin(__builtin_amdgcn_exp2f)
__device__ __forceinline__ float fexp2(float x) { return __builtin_amdgcn_exp2f(x); }
#else
__device__ __forceinline__ float fexp2(float x) { return __expf(x * LN2); }
#endif
#if __has_builtin(__builtin_amdgcn_logf)
__device__ __forceinline__ float flog2(float x) { return __builtin_amdgcn_logf(x); }
#else
__device__ __forceinline__ float flog2(float x) { return __logf(x) * LOG2E; }
#endif

__device__ __forceinline__ float dpp_shr1(float x, float oldv) {
  // wave_shr:1 -- lane i gets lane i-1's x; lane 0 keeps `oldv`.
  return __int_as_float(__builtin_amdgcn_update_dpp(
      __float_as_int(oldv), __float_as_int(x), 0x138, 0xF, 0xF, false));
}
__device__ __forceinline__ float dpp_shl1(float x, float oldv) {
  // wave_shl:1 -- lane i gets lane i+1's x; lane 63 keeps `oldv`.
  return __int_as_float(__builtin_amdgcn_update_dpp(
      __float_as_int(oldv), __float_as_int(x), 0x130, 0xF, 0xF, false));
}
// lse2 via max+log1p-style: 1 exp + 1 log (saves 1 exp vs 2-exp form).
__device__ __forceinline__ float lse2(float a, float b) {
  return fmaxf(a, b) + flog2(1.f + fexp2(-fabsf(a - b)));
}

// 2x17 staging registers as NAMED scalars (no alloca!): P0..P15 labels, Pb blank.
#define DECL17(P)                                                           \
  float P##0, P##1, P##2, P##3, P##4, P##5, P##6, P##7, P##8, P##9, P##10,  \
      P##11, P##12, P##13, P##14, P##15, P##b;

// Byte offsets: t*B*C*4 = t<<17; labBase = b<<10 | cls<<2; blkBase = b<<10.
#define LOADF(P, c_, k_)                                                    \
  {                                                                         \
    const int t_ = min(1 + (c_)*K + k_, m); /* clamp: addr ok, unused */    \
    const unsigned off_ = labBase + ((unsigned)t_ << 17);                   \
    asm volatile("global_load_dword %0, %1, %2"                             \
                 : "=v"(P##k_) : "v"(off_), "s"(lp));                       \
  }
#define LOADB(P, c_, k_)                                                    \
  {                                                                         \
    const int t_ = max(len - 2 - ((c_)*K + k_), 0);                         \
    const unsigned off_ = labBase + ((unsigned)t_ << 17);                   \
    asm volatile("global_load_dword %0, %1, %2"                             \
                 : "=v"(P##k_) : "v"(off_), "s"(lp));                       \
  }
#define ISSUEF(P, c_)                                                       \
  do {                                                                      \
    LOADF(P, c_, 0) LOADF(P, c_, 1) LOADF(P, c_, 2) LOADF(P, c_, 3)         \
    LOADF(P, c_, 4) LOADF(P, c_, 5) LOADF(P, c_, 6) LOADF(P, c_, 7)         \
    LOADF(P, c_, 8) LOADF(P, c_, 9) LOADF(P, c_, 10) LOADF(P, c_, 11)       \
    LOADF(P, c_, 12) LOADF(P, c_, 13) LOADF(P, c_, 14) LOADF(P, c_, 15)     \
    {                                                                       \
      const int tb_ = min(1 + (c_)*K + lane, m);                            \
      const unsigned offb_ = blkBase + ((unsigned)tb_ << 17);               \
      asm volatile("global_load_dword %0, %1, %2"                           \
                   : "=v"(P##b) : "v"(offb_), "s"(lp));                     \
    }                                                                       \
  } while (0)
#define ISSUEB(P, c_)                                                       \
  do {                                                                      \
    LOADB(P, c_, 0) LOADB(P, c_, 1) LOADB(P, c_, 2) LOADB(P, c_, 3)         \
    LOADB(P, c_, 4) LOADB(P, c_, 5) LOADB(P, c_, 6) LOADB(P, c_, 7)         \
    LOADB(P, c_, 8) LOADB(P, c_, 9) LOADB(P, c_, 10) LOADB(P, c_, 11)       \
    LOADB(P, c_, 12) LOADB(P, c_, 13) LOADB(P, c_, 14) LOADB(P, c_, 15)     \
    {                                                                       \
      const int tb_ = max(len - 2 - (c_)*K - lane, 0);                      \
      const unsigned offb_ = blkBase + ((unsigned)tb_ << 17);               \
      asm volatile("global_load_dword %0, %1, %2"                           \
                   : "=v"(P##b) : "v"(offb_), "s"(lp));                     \
    }                                                                       \
  } while (0)

// "+v" ties REDEFINE the staging regs so no use can float above the wait.
#define WAITTIE(P)                                                          \
  asm volatile("s_waitcnt vmcnt(17)"                                        \
               : "+v"(P##0), "+v"(P##1), "+v"(P##2), "+v"(P##3),            \
                 "+v"(P##4), "+v"(P##5), "+v"(P##6), "+v"(P##7),            \
                 "+v"(P##8), "+v"(P##9), "+v"(P##10), "+v"(P##11),          \
                 "+v"(P##12), "+v"(P##13), "+v"(P##14), "+v"(P##15),        \
                 "+v"(P##b))

// Forward step (log2 domain). a0=alpha[0] (uniform); lane i: o=alpha[2i+1],
// v=alpha[2i+2].
#define STEPF(P, k_)                                                        \
  if (k_ < kend_) {                                                         \
    const float sb_ = __int_as_float(                                       \
        __builtin_amdgcn_readlane(__float_as_int(blsc_), k_));              \
    const float lw_ = P##k_ * LOG2E;                                        \
    const float ev2_ = dpp_shr1(v, a0);  /* alpha[2i]   */                  \
    const float od2_ = dpp_shr1(o, NEG); /* alpha[2i-1] */                  \
    const float p2_ = sameAsPrev ? NEG : od2_;                              \
    const float m1_ = fmaxf(o, fmaxf(ev2_, p2_));                           \
    const float s1_ =                                                       \
        fexp2(o - m1_) + fexp2(ev2_ - m1_) + fexp2(p2_ - m1_);              \
    const float no_ = m1_ + flog2(s1_) + lw_;                               \
    const float nv_ = lse2(v, o) + sb_;                                     \
    a0 += sb_;                                                              \
    o = no_;                                                                \
    v = nv_;                                                                \
  }
// Backward step. a0b=beta[128] (uniform); lane j: ob=beta[2j+1], eb=beta[2j].
//   ob' = lse(ob, eb@(j+1) [j=63 -> a0b], [allowB] ob@(j+1)) + lpl_j
//   eb' = lse(eb, ob) + lpb     a0b' = a0b + lpb
#define STEPB(P, k_)                                                        \
  if (k_ < kend_) {                                                         \
    const float sb_ = __int_as_float(                                       \
        __builtin_amdgcn_readlane(__float_as_int(blsc_), k_));              \
    const float lw_ = P##k_ * LOG2E;                                        \
    const float es_ = dpp_shl1(eb, a0b); /* beta[2j+2]; lane63 -> beta[128] */\
    const float os_ = dpp_shl1(ob, NEG); /* beta[2j+3] */                   \
    const float p2_ = allowB ? os_ : NEG;                                   \
    const float m1_ = fmaxf(ob, fmaxf(es_, p2_));                           \
    const float s1_ =                                                       \
        fexp2(ob - m1_) + fexp2(es_ - m1_) + fexp2(p2_ - m1_);              \
    const float no_ = m1_ + flog2(s1_) + lw_;                               \
    const float ne_ = lse2(eb, ob) + sb_;                                   \
    a0b += sb_;                                                             \
    ob = no_;                                                               \
    eb = ne_;                                                               \
  }

#define COMPUTEF(P, c_)                                                     \
  do {                                                                      \
    const float blsc_ = (P##b)*LOG2E;                                       \
    const int kend_ = stepsN - (c_)*K;                                      \
    STEPF(P, 0) STEPF(P, 1) STEPF(P, 2) STEPF(P, 3) STEPF(P, 4) STEPF(P, 5) \
    STEPF(P, 6) STEPF(P, 7) STEPF(P, 8) STEPF(P, 9) STEPF(P, 10)            \
    STEPF(P, 11) STEPF(P, 12) STEPF(P, 13) STEPF(P, 14) STEPF(P, 15)        \
  } while (0)
#define COMPUTEB(P, c_)                                                     \
  do {                                                                      \
    const float blsc_ = (P##b)*LOG2E;                                       \
    const int kend_ = stepsN - (c_)*K;                                      \
    STEPB(P, 0) STEPB(P, 1) STEPB(P, 2) STEPB(P, 3) STEPB(P, 4) STEPB(P, 5) \
    STEPB(P, 6) STEPB(P, 7) STEPB(P, 8) STEPB(P, 9) STEPB(P, 10)            \
    STEPB(P, 11) STEPB(P, 12) STEPB(P, 13) STEPB(P, 14) STEPB(P, 15)        \
  } while (0)

// ---------------------------------------------------------------------------
__global__ __launch_bounds__(256, 1) void k_fused(
    const float* __restrict__ lp, const int* __restrict__ targets,
    const int* __restrict__ in_len, const int* __restrict__ tg_len,
    float* __restrict__ ent_part, float* __restrict__ nll_out) {
  __shared__ float wsum[4];
  __shared__ float Ast[129], Bst[129], red[4];
  const int tid = threadIdx.x;

  if (blockIdx.x < ENT_GRID) {
    // ---------------- entropy path ----------------
    const size_t N4 = (size_t)T * B * C / 4;
    const float4* lp4 = (const float4*)lp;
    const size_t stride = (size_t)ENT_GRID * 256;
    float a0 = 0.f, a1 = 0.f, a2 = 0.f, a3 = 0.f;
    for (size_t i = (size_t)blockIdx.x * 256 + tid; i < N4; i += stride) {
      const float4 vv = lp4[i];
      a0 += vv.x * __expf(vv.x);
      a1 += vv.y * __expf(vv.y);
      a2 += vv.z * __expf(vv.z);
      a3 += vv.w * __expf(vv.w);
    }
    float ent = (a0 + a1) + (a2 + a3);
    for (int off = 32; off > 0; off >>= 1) ent += __shfl_down(ent, off, 64);
    if ((tid & 63) == 0) wsum[tid >> 6] = ent;
    __syncthreads();
    if (tid == 0) ent_part[blockIdx.x] = wsum[0] + wsum[1] + wsum[2] + wsum[3];
    return;
  }

  // ---------------- CTC path: wave0 = alpha, wave1 = beta ----------------
  if (tid >= 128) return;
  const int b = blockIdx.x - ENT_GRID;
  const int wave = tid >> 6;
  const int lane = tid & 63;
  const int len = in_len[b];        // [512, 1024]
  const int tl = tg_len[b];         // [32, 64]
  const int m = (len - 1) >> 1;     // meeting point

  const int cls = targets[b * L + lane];
  const unsigned labBase = ((unsigned)b << 10) + ((unsigned)cls << 2);
  const unsigned blkBase = ((unsigned)b << 10);

  DECL17(X)
  DECL17(Y)

  if (wave == 0) {
    // ======== alpha: t = 1..m ========
    const int stepsN = m;
    const int nch = (stepsN + K - 1) / K;
    const int prevc = (lane == 0) ? -1 : targets[b * L + lane - 1];
    const bool sameAsPrev = (cls == prevc);
    const float lpb0 = lp[(size_t)b * C];
    const float lpl0 = lp[(size_t)b * C + cls];
    float a0 = lpb0 * LOG2E;
    float o = (lane == 0) ? lpl0 * LOG2E : NEG;
    float v = NEG;
    asm volatile("s_waitcnt vmcnt(0) lgkmcnt(0)" ::: "memory");
    ISSUEF(X, 0);
    int c = 0;
    for (;;) {
      ISSUEF(Y, c + 1);
      WAITTIE(X);
      COMPUTEF(X, c);
      ++c;
      if (c == nch) break;
      ISSUEF(X, c + 1);
      WAITTIE(Y);
      COMPUTEF(Y, c);
      ++c;
      if (c == nch) break;
    }
    asm volatile("s_waitcnt vmcnt(0)" ::: "memory");
    if (lane == 0) Ast[0] = a0;
    Ast[2 * lane + 1] = o;
    Ast[2 * lane + 2] = v;
  } else {
    // ======== beta: init at t=len-1, steps t = len-2 .. m ========
    const int stepsN = len - 1 - m;
    const int nch = (stepsN + K - 1) / K;
    const int nxtc = targets[b * L + min(lane + 1, L - 1)];
    const bool allowB = (lane < 63) && (nxtc != cls);
    const size_t rowE = (size_t)(len - 1) * (B * C) + (size_t)b * C;
    const float lpbE = lp[rowE] * LOG2E;
    const float lplE = lp[rowE + cls] * LOG2E;
    float a0b = (tl == L) ? lpbE : NEG;                  // beta[128]
    float ob = (lane == tl - 1) ? lplE : NEG;            // beta[2tl-1]
    float eb = (lane == tl && tl < L) ? lpbE : NEG;      // beta[2tl]
    asm volatile("s_waitcnt vmcnt(0) lgkmcnt(0)" ::: "memory");
    ISSUEB(X, 0);
    int c = 0;
    for (;;) {
      ISSUEB(Y, c + 1);
      WAITTIE(X);
      COMPUTEB(X, c);
      ++c;
      if (c == nch) break;
      ISSUEB(X, c + 1);
      WAITTIE(Y);
      COMPUTEB(Y, c);
      ++c;
      if (c == nch) break;
    }
    asm volatile("s_waitcnt vmcnt(0)" ::: "memory");
    if (lane == 0) Bst[128] = a0b;
    Bst[2 * lane + 1] = ob;
    Bst[2 * lane] = eb;
  }
  __syncthreads();

  // ---- combine: ll = lse_s(alpha_m[s] + beta_m[s] - lp_m[s]) over 129 s ----
  const size_t rowM = (size_t)m * (B * C) + (size_t)b * C;
  const int scls = (tid & 1) ? targets[b * L + (tid >> 1)] : 0;
  float val = Ast[tid] + Bst[tid] - lp[rowM + scls] * LOG2E;
  if (tid == 0) {
    const float v128 = Ast[128] + Bst[128] - lp[rowM] * LOG2E;
    const float mm = fmaxf(val, v128);
    val = mm + flog2(fexp2(val - mm) + fexp2(v128 - mm));
  }
  float mx = val;
  for (int off = 32; off > 0; off >>= 1)
    mx = fmaxf(mx, __shfl_xor(mx, off, 64));
  if (lane == 0) red[wave] = mx;
  __syncthreads();
  mx = fmaxf(red[0], red[1]);
  float ex = fexp2(val - mx);
  for (int off = 32; off > 0; off >>= 1) ex += __shfl_xor(ex, off, 64);
  if (lane == 0) red[2 + wave] = ex;
  __syncthreads();
  if (tid == 0) {
    const float ll = (mx + flog2(red[2] + red[3])) * LN2;
    float nll = -ll;
    if (nll > 1e29f) nll = 0.f;  // zero_infinity
    nll_out[b] = nll;
  }
}

// ---------------------------------------------------------------------------
__global__ __launch_bounds__(256) void k_final(
    const float* __restrict__ ent_part, const float* __restrict__ nll,
    float* __restrict__ out) {
  const int tid = threadIdx.x;
  float s = 0.f;
  for (int i = tid; i < ENT_GRID; i += 256) s += ent_part[i];
  float n = (tid < B) ? nll[tid] : 0.f;
  for (int off = 32; off > 0; off >>= 1) {
    s += __shfl_down(s, off, 64);
    n += __shfl_down(n, off, 64);
  }
  __shared__ float ss[4], nn[4];
  if ((tid & 63) == 0) { ss[tid >> 6] = s; nn[tid >> 6] = n; }
  __syncthreads();
  if (tid == 0) {
    const float ent_sum = ss[0] + ss[1] + ss[2] + ss[3];
    const float nll_sum = nn[0] + nn[1] + nn[2] + nn[3];
    const float ctc_mean = nll_sum / (float)B;
    const float smooth = ent_sum / (float)(T * B);  // = -entropy.mean()
    out[0] = 0.9f * ctc_mean + 0.1f * smooth;
  }
}

extern "C" void kernel_launch(void* const* d_in, const int* in_sizes, int n_in,
                              void* d_out, int out_size, void* d_ws, size_t ws_size,
                              hipStream_t stream) {
  const float* lp      = (const float*)d_in[0];  // [T,B,C] f32
  const int*   targets = (const int*)d_in[1];    // [B,L] i32
  const int*   in_len  = (const int*)d_in[2];    // [B] i32
  const int*   tg_len  = (const int*)d_in[3];    // [B] i32
  float* out = (float*)d_out;
  float* ws  = (float*)d_ws;

  float* ent_part = ws;             // [1024]
  float* nllb     = ws + ENT_GRID;  // [128]

  k_fused<<<ENT_GRID + B, 256, 0, stream>>>(lp, targets, in_len, tg_len,
                                            ent_part, nllb);
  k_final<<<1, 256, 0, stream>>>(ent_part, nllb, out);
}